// Round 1
// baseline (123.928 us; speedup 1.0000x reference)
//
#include <hip/hip_runtime.h>

// LIF scan: o[t,n] = spike(u_t), u recurrence over t (64 steps), 1M neurons.
// Memory-bound streaming: 256 MB in + 256 MB out. One thread owns 4 neurons
// (float4 lanes), loops over time; per-timestep accesses are fully coalesced
// (lane i touches bytes [16i, 16i+16) of each 4 MB time-plane).
//
// Rounding discipline: reference computes du = 0.5f*(ir - u); u_t = du + u as
// SEPARATE float32 ops. __f*_rn intrinsics prevent -ffp-contract=fast from
// fusing into fma, which would flip threshold crossings near u_t == 1.0 and
// corrupt entire neuron trajectories (spike reset is history-dependent).

constexpr int T_STEPS = 64;
constexpr int NS      = 32 * 32768;   // neurons per timestep
constexpr int NS4     = NS / 4;       // float4 chunks per timestep

__global__ __launch_bounds__(256)
void LIF_61263413510486_kernel(const float* __restrict__ ir,
                               float* __restrict__ o) {
    const int i = blockIdx.x * blockDim.x + threadIdx.x;  // float4 index in a time-plane
    const float4* __restrict__ ir4 = reinterpret_cast<const float4*>(ir);
    float4* __restrict__ o4 = reinterpret_cast<float4*>(o);

    float u[4] = {0.0f, 0.0f, 0.0f, 0.0f};

    #pragma unroll 8
    for (int t = 0; t < T_STEPS; ++t) {
        const float4 x = ir4[(size_t)t * NS4 + i];
        const float xs[4] = {x.x, x.y, x.z, x.w};
        float os[4];
        #pragma unroll
        for (int j = 0; j < 4; ++j) {
            // du = (1/tau)*( -(u - u_rest) + ir ) with tau=2, u_rest=0
            const float du = __fmul_rn(0.5f, __fsub_rn(xs[j], u[j]));
            const float ut = __fadd_rn(du, u[j]);
            const bool spike = (ut >= 1.0f);   // heaviside(u_t - 1.0)
            os[j] = spike ? 1.0f : 0.0f;
            u[j]  = spike ? 0.0f : ut;         // exact: u*(1-o) + 0*o
        }
        o4[(size_t)t * NS4 + i] = make_float4(os[0], os[1], os[2], os[3]);
    }
}

extern "C" void kernel_launch(void* const* d_in, const int* in_sizes, int n_in,
                              void* d_out, int out_size, void* d_ws, size_t ws_size,
                              hipStream_t stream) {
    const float* ir = (const float*)d_in[0];
    float* o = (float*)d_out;

    const int threads = 256;
    const int blocks  = NS4 / threads;   // 262144 / 256 = 1024 blocks
    LIF_61263413510486_kernel<<<blocks, threads, 0, stream>>>(ir, o);
}

// Round 2
// 118.825 us; speedup vs baseline: 1.0429x; 1.0429x over previous
//
#include <hip/hip_runtime.h>

// LIF scan over t=0..63, 1M neurons, float32. Memory-bound streaming:
// 256 MB read + 256 MB write, zero reuse. Round-1 kernel hit 4.13 TB/s
// (124 us); copy ceiling is ~6.3 TB/s (~81 us). Bottleneck: bytes in
// flight (16 waves/CU x ~8 loads x 16B = 2KB/CU; need 4-9KB).
//
// This version: explicit double-buffered batches of 8 time-plane loads
// (steady-state 8-16 float4 loads in flight per wave), fully unrolled so
// every buffer index is compile-time (runtime-indexed reg arrays spill to
// scratch). Non-temporal load/store: 512 MB streamed once, no reuse --
// skip L2/L3 allocation.
//
// Rounding discipline: reference computes du = 0.5f*(ir - u); u_t = du + u
// as SEPARATE fp32 ops; __f*_rn blocks fma contraction which would flip
// threshold crossings (history-dependent spike reset => trajectory forks).

typedef float f32x4 __attribute__((ext_vector_type(4)));

constexpr int T_STEPS = 64;
constexpr int NS      = 32 * 32768;   // neurons per timestep
constexpr int NS4     = NS / 4;       // float4 chunks per timestep
constexpr int BATCH   = 8;
constexpr int NBATCH  = T_STEPS / BATCH;   // 8

__global__ __launch_bounds__(256)
void LIF_61263413510486_kernel(const float* __restrict__ ir,
                               float* __restrict__ o) {
    const int i = blockIdx.x * blockDim.x + threadIdx.x;  // float4 index in plane
    const f32x4* __restrict__ src = reinterpret_cast<const f32x4*>(ir) + i;
    f32x4* __restrict__ dst = reinterpret_cast<f32x4*>(o) + i;

    f32x4 buf[2][BATCH];
    float u[4] = {0.0f, 0.0f, 0.0f, 0.0f};

    // prologue: batch 0 in flight
    #pragma unroll
    for (int k = 0; k < BATCH; ++k)
        buf[0][k] = __builtin_nontemporal_load(src + (size_t)k * NS4);

    #pragma unroll
    for (int tb = 0; tb < NBATCH; ++tb) {
        const int cur = tb & 1;        // compile-time after full unroll
        const int nxt = cur ^ 1;
        if (tb + 1 < NBATCH) {
            #pragma unroll
            for (int k = 0; k < BATCH; ++k)
                buf[nxt][k] = __builtin_nontemporal_load(
                    src + (size_t)((tb + 1) * BATCH + k) * NS4);
        }
        #pragma unroll
        for (int k = 0; k < BATCH; ++k) {
            const f32x4 x = buf[cur][k];
            f32x4 ov;
            #pragma unroll
            for (int j = 0; j < 4; ++j) {
                const float du = __fmul_rn(0.5f, __fsub_rn(x[j], u[j]));
                const float ut = __fadd_rn(du, u[j]);
                const bool spike = (ut >= 1.0f);   // heaviside(u_t - 1.0)
                ov[j] = spike ? 1.0f : 0.0f;
                u[j]  = spike ? 0.0f : ut;          // u*(1-o) + 0*o exactly
            }
            __builtin_nontemporal_store(ov, dst + (size_t)(tb * BATCH + k) * NS4);
        }
    }
}

extern "C" void kernel_launch(void* const* d_in, const int* in_sizes, int n_in,
                              void* d_out, int out_size, void* d_ws, size_t ws_size,
                              hipStream_t stream) {
    const float* ir = (const float*)d_in[0];
    float* o = (float*)d_out;

    const int threads = 256;
    const int blocks  = NS4 / threads;   // 1024
    LIF_61263413510486_kernel<<<blocks, threads, 0, stream>>>(ir, o);
}

// Round 3
// 102.337 us; speedup vs baseline: 1.2110x; 1.1611x over previous
//
#include <hip/hip_runtime.h>

// LIF scan over t=0..63, 1M neurons, fp32. Streaming 256 MB in + 256 MB out.
// R1 (float4, 16 waves/CU): 124 us. R2 (+dbuf, fat VGPR): 119 us = 4.5 TB/s,
// 71% of copy ceiling. MLP was never the limit (Little's law needs ~9 KB/CU
// in flight; we had >100 KB). New theory: TLP -- float4 granularity caps the
// grid at 16 waves/CU and R2's 64-VGPR buffers likely cost a block/CU.
//
// This version: float2 per thread -> 8192 waves = 32 waves/CU (max occupancy),
// slim BATCH=4 double buffer (~16 VGPR of data), __launch_bounds__(256,8)
// pins VGPR <= 64 so 8 waves/SIMD actually fit. Coalescing intact: 64 lanes
// x 8 B = 512 B contiguous per wave-load. Non-temporal on both streams
// (zero reuse; don't thrash 32 MB L2 with 512 MB of traffic).
//
// Rounding discipline unchanged (absmax == 0 in R1/R2): du = 0.5*(ir-u) and
// u_t = du + u as separate __f*_rn ops; fma contraction would flip threshold
// crossings and fork entire neuron trajectories.

typedef float f32x2 __attribute__((ext_vector_type(2)));

constexpr int T_STEPS = 64;
constexpr int NS      = 32 * 32768;     // neurons per timestep
constexpr int NS2     = NS / 2;         // float2 chunks per timestep (524288)
constexpr int BATCH   = 4;
constexpr int NBATCH  = T_STEPS / BATCH;   // 16

__global__ __launch_bounds__(256, 8)
void LIF_61263413510486_kernel(const float* __restrict__ ir,
                               float* __restrict__ o) {
    const int i = blockIdx.x * blockDim.x + threadIdx.x;  // float2 index in plane
    const f32x2* __restrict__ src = reinterpret_cast<const f32x2*>(ir) + i;
    f32x2* __restrict__ dst = reinterpret_cast<f32x2*>(o) + i;

    f32x2 buf[2][BATCH];
    float u[2] = {0.0f, 0.0f};

    #pragma unroll
    for (int k = 0; k < BATCH; ++k)
        buf[0][k] = __builtin_nontemporal_load(src + (size_t)k * NS2);

    #pragma unroll
    for (int tb = 0; tb < NBATCH; ++tb) {
        const int cur = tb & 1;        // compile-time after full unroll
        const int nxt = cur ^ 1;
        if (tb + 1 < NBATCH) {
            #pragma unroll
            for (int k = 0; k < BATCH; ++k)
                buf[nxt][k] = __builtin_nontemporal_load(
                    src + (size_t)((tb + 1) * BATCH + k) * NS2);
        }
        #pragma unroll
        for (int k = 0; k < BATCH; ++k) {
            const f32x2 x = buf[cur][k];
            f32x2 ov;
            #pragma unroll
            for (int j = 0; j < 2; ++j) {
                const float du = __fmul_rn(0.5f, __fsub_rn(x[j], u[j]));
                const float ut = __fadd_rn(du, u[j]);
                const bool spike = (ut >= 1.0f);   // heaviside(u_t - 1.0)
                ov[j] = spike ? 1.0f : 0.0f;
                u[j]  = spike ? 0.0f : ut;          // u*(1-o) + 0*o exactly
            }
            __builtin_nontemporal_store(ov, dst + (size_t)(tb * BATCH + k) * NS2);
        }
    }
}

extern "C" void kernel_launch(void* const* d_in, const int* in_sizes, int n_in,
                              void* d_out, int out_size, void* d_ws, size_t ws_size,
                              hipStream_t stream) {
    const float* ir = (const float*)d_in[0];
    float* o = (float*)d_out;

    const int threads = 256;
    const int blocks  = NS2 / threads;   // 2048
    LIF_61263413510486_kernel<<<blocks, threads, 0, stream>>>(ir, o);
}